// Round 6
// baseline (99.758 us; speedup 1.0000x reference)
//
#include <hip/hip_runtime.h>
#include <hip/hip_bf16.h>

#define Bq 4
#define Tq 4096
#define Cq 512
#define Hq 64
#define NCH 8            // chunks per q-tile (KC = 512 = 16 tiles of 32)
#define CT 16            // k-tiles (32-wide) per chunk
#define NEG_BIG (-3.0e38f)

using bf16   = __bf16;
using bf16x8 = __attribute__((ext_vector_type(8))) __bf16;
using bf16x4 = __attribute__((ext_vector_type(4))) __bf16;
using f32x4  = __attribute__((ext_vector_type(4))) float;
using f32x16 = __attribute__((ext_vector_type(16))) float;

// ---- cross-half (lane ^ 32) exchange: proven __shfl_xor primitive ----
static __device__ __forceinline__ float other_half_f(float x) {
    return __shfl_xor(x, 32, 64);
}
static __device__ __forceinline__ unsigned other_half_u(unsigned x) {
    return (unsigned)__shfl_xor((int)x, 32, 64);
}
static __device__ __forceinline__ unsigned pk2(float x, float y) {
    union { bf16 h[2]; unsigned u; } t;
    t.h[0] = (bf16)x; t.h[1] = (bf16)y;
    return t.u;
}
union W8 { unsigned u[4]; bf16x8 v; };

// ---------------------------------------------------------------------------
// Kernel 1: transpose + bf16-cast the three weight matrices: WT[t][h][c]
// ---------------------------------------------------------------------------
__global__ __launch_bounds__(256) void prep_weights_kernel(
    const float* __restrict__ kW, const float* __restrict__ qW,
    const float* __restrict__ vW, bf16* __restrict__ WT)
{
    int i = blockIdx.x * 256 + threadIdx.x;   // 3*64*512 = 98304 total
    int t = i >> 15;
    int r = i & 32767;
    int h = r >> 9;
    int c = r & 511;
    const float* W = (t == 0) ? kW : (t == 1) ? qW : vW;
    WT[i] = (bf16)W[c * Hq + h];
}

// ---------------------------------------------------------------------------
// Kernel 2: projections via MFMA 16x16x32 bf16 (unchanged from round 4).
// ---------------------------------------------------------------------------
__global__ __launch_bounds__(256) void proj_kernel(
    const float* __restrict__ Xk, const float* __restrict__ Xq,
    const float* __restrict__ Xv, const bf16* __restrict__ WT,
    const float* __restrict__ bk, const float* __restrict__ bq,
    const float* __restrict__ bv,
    bf16* __restrict__ kp, bf16* __restrict__ qp, bf16* __restrict__ vpT)
{
    const int t    = blockIdx.y;
    const int lane = threadIdx.x & 63;
    const int wave = threadIdx.x >> 6;
    const int lq   = lane & 15;
    const int lg   = lane >> 4;
    const int row0 = blockIdx.x * 64 + wave * 16;

    const float* X    = (t == 0) ? Xk : (t == 1) ? Xq : Xv;
    const float* bias = (t == 0) ? bk : (t == 1) ? bq : bv;
    const bf16*  Wt   = WT + (size_t)t * (Hq * Cq);

    const float* Xrow = X + (size_t)(row0 + lq) * Cq + lg * 8;

    f32x4 acc[4];
#pragma unroll
    for (int i = 0; i < 4; ++i) acc[i] = f32x4{0.f, 0.f, 0.f, 0.f};

#pragma unroll 4
    for (int kc = 0; kc < Cq; kc += 32) {
        float4 a0 = *(const float4*)(Xrow + kc);
        float4 a1 = *(const float4*)(Xrow + kc + 4);
        bf16x8 af;
        af[0] = (bf16)a0.x; af[1] = (bf16)a0.y; af[2] = (bf16)a0.z; af[3] = (bf16)a0.w;
        af[4] = (bf16)a1.x; af[5] = (bf16)a1.y; af[6] = (bf16)a1.z; af[7] = (bf16)a1.w;
#pragma unroll
        for (int ht = 0; ht < 4; ++ht) {
            bf16x8 bfB = *(const bf16x8*)(Wt + (size_t)(ht * 16 + lq) * Cq + kc + lg * 8);
            acc[ht] = __builtin_amdgcn_mfma_f32_16x16x32_bf16(af, bfB, acc[ht], 0, 0, 0);
        }
    }

    const float scale = (t == 1) ? 0.044194173824159216f : 1.0f;

    if (t < 2) {
        bf16* dst = (t == 0) ? kp : qp;
#pragma unroll
        for (int ht = 0; ht < 4; ++ht) {
            float bb = bias[ht * 16 + lq];
#pragma unroll
            for (int r = 0; r < 4; ++r) {
                int row = row0 + 4 * lg + r;
                dst[(size_t)row * Hq + ht * 16 + lq] = (bf16)((acc[ht][r] + bb) * scale);
            }
        }
    } else {
#pragma unroll
        for (int ht = 0; ht < 4; ++ht) {
            float bb = bias[ht * 16 + lq];
            bf16x4 pk;
#pragma unroll
            for (int r = 0; r < 4; ++r) pk[r] = (bf16)(acc[ht][r] + bb);
            int rowg = row0 + 4 * lg;
            int bidx = rowg >> 12;
            int tt   = rowg & 4095;
            int h    = ht * 16 + lq;
            *(bf16x4*)(vpT + (((size_t)(bidx * Hq + h)) << 12) + tt) = pk;
        }
    }
}

// ---------------------------------------------------------------------------
// Kernel 3: causal flash attention, split-K, 32x32x16 MFMA, IN-REGISTER
// softmax (zero LDS).  One wave per (b, 32-row q-tile, 512-k chunk).
//   S^T = mfma(K, Q):  D col = q = lane&31,  row = k = (reg&3)+8(reg>>2)+4*half
//   => all 16 k-values for a q live IN-LANE; cross-lane reduce is ONE
//      __shfl_xor(.,32) per stat.  All sentinels FINITE (-3e38): no inf-inf.
//   P -> PV B-operand: pack bf16 pairs, 8 xor-32 shuffles + selects.
//   O^T accumulated as two 32x32 tiles (h 0..31, 32..63).
// ---------------------------------------------------------------------------
__global__ __launch_bounds__(64) void attn_kernel(
    const bf16* __restrict__ qp, const bf16* __restrict__ kp,
    const bf16* __restrict__ vpT,
    bf16* __restrict__ PO, float* __restrict__ PML)
{
    const int x = blockIdx.x;                 // 512 = 4 batches x 128 q-tiles
    const int s = x & 7;                      // XCD slot
    const int b = s >> 1;                     // batch pinned to XCD pair
    const int a = ((x >> 3) << 1) | (s & 1);  // 0..127: 32-row q-tile index
    const int qb = a * 32;
    const int c = blockIdx.y;
    if (c * CT > a) return;                   // chunk entirely above diagonal

    const int lane = threadIdx.x;
    const int l31  = lane & 31;
    const int half = lane >> 5;
    const bool hi  = half != 0;

    // Q fragments: B[col=q=l31][contraction h = h0 + half*8 + i], h0=0,16,32,48
    const bf16* qrow = qp + ((size_t)b * Tq + qb + l31) * Hq + half * 8;
    const bf16x8 Q0 = *(const bf16x8*)(qrow);
    const bf16x8 Q1 = *(const bf16x8*)(qrow + 16);
    const bf16x8 Q2 = *(const bf16x8*)(qrow + 32);
    const bf16x8 Q3 = *(const bf16x8*)(qrow + 48);

    const bf16* Kb = kp  + (size_t)b * Tq * Hq;
    const bf16* Vb = vpT + (size_t)b * Hq * Tq;

    f32x16 O0, O1;
#pragma unroll
    for (int r = 0; r < 16; ++r) { O0[r] = 0.f; O1[r] = 0.f; }
    float m = NEG_BIG, l = 0.f;

    const int t0 = c * CT;
    const int t1 = min(a, t0 + CT - 1);

    for (int it = t0; it <= t1; ++it) {
        const int kb0 = it * 32;

        // K A-frags: A[row=k_local=l31][contraction h = h0 + half*8 + i]
        const bf16* kr = Kb + (size_t)(kb0 + l31) * Hq + half * 8;
        const bf16x8 K0 = *(const bf16x8*)(kr);
        const bf16x8 K1 = *(const bf16x8*)(kr + 16);
        const bf16x8 K2 = *(const bf16x8*)(kr + 32);
        const bf16x8 K3 = *(const bf16x8*)(kr + 48);
        // V A-frags: A[row=h_local=l31][contraction k = ksub + half*8 + i]
        const bf16* vr = Vb + (size_t)l31 * Tq + kb0 + half * 8;
        const bf16x8 V00 = *(const bf16x8*)(vr);
        const bf16x8 V01 = *(const bf16x8*)(vr + 16);
        const bf16x8 V10 = *(const bf16x8*)(vr + (size_t)32 * Tq);
        const bf16x8 V11 = *(const bf16x8*)(vr + (size_t)32 * Tq + 16);

        // ---- S^T = K * Q^T over H=64 (4 MFMAs of K=16) ----
        f32x16 S;
#pragma unroll
        for (int r = 0; r < 16; ++r) S[r] = 0.f;
        __builtin_amdgcn_s_setprio(1);
        S = __builtin_amdgcn_mfma_f32_32x32x16_bf16(K0, Q0, S, 0, 0, 0);
        S = __builtin_amdgcn_mfma_f32_32x32x16_bf16(K1, Q1, S, 0, 0, 0);
        S = __builtin_amdgcn_mfma_f32_32x32x16_bf16(K2, Q2, S, 0, 0, 0);
        S = __builtin_amdgcn_mfma_f32_32x32x16_bf16(K3, Q3, S, 0, 0, 0);
        __builtin_amdgcn_s_setprio(0);

        // ---- causal mask (diagonal tile only): k = kb0+(r&3)+8(r>>2)+4*half
        if (it == a) {
#pragma unroll
            for (int r = 0; r < 16; ++r) {
                const int kg = kb0 + (r & 3) + 8 * (r >> 2) + 4 * half;
                if (kg > qb + l31) S[r] = NEG_BIG;
            }
        }

        // ---- online softmax, per q = l31, 16 k-values in-lane ----
        float tm = S[0];
#pragma unroll
        for (int r = 1; r < 16; ++r) tm = fmaxf(tm, S[r]);
        tm = fmaxf(tm, other_half_f(tm));
        const float mn   = fmaxf(m, tm);
        const float corr = __expf(m - mn);    // finite - finite: no NaN
        float p[16];
        float ps = 0.f;
#pragma unroll
        for (int r = 0; r < 16; ++r) { p[r] = __expf(S[r] - mn); ps += p[r]; }
        ps += other_half_f(ps);
        l = l * corr + ps;
        m = mn;
#pragma unroll
        for (int r = 0; r < 16; ++r) { O0[r] *= corr; O1[r] *= corr; }

        // ---- P -> bf16 words; build PV B-frags via xor-32 shuffles ----
        const unsigned w0 = pk2(p[0],  p[1]),  w1 = pk2(p[2],  p[3]);
        const unsigned w2 = pk2(p[4],  p[5]),  w3 = pk2(p[6],  p[7]);
        const unsigned w4 = pk2(p[8],  p[9]),  w5 = pk2(p[10], p[11]);
        const unsigned w6 = pk2(p[12], p[13]), w7 = pk2(p[14], p[15]);
        const unsigned o0 = other_half_u(w0), o1 = other_half_u(w1);
        const unsigned o2 = other_half_u(w2), o3 = other_half_u(w3);
        const unsigned o4 = other_half_u(w4), o5 = other_half_u(w5);
        const unsigned o6 = other_half_u(w6), o7 = other_half_u(w7);
        // B[contraction k = half*8 + i][col=q]
        W8 B0, B1;
        B0.u[0] = hi ? o2 : w0;  B0.u[1] = hi ? o3 : w1;   // k 0..7 / 8..15
        B0.u[2] = hi ? w2 : o0;  B0.u[3] = hi ? w3 : o1;
        B1.u[0] = hi ? o6 : w4;  B1.u[1] = hi ? o7 : w5;   // k 16..23 / 24..31
        B1.u[2] = hi ? w6 : o4;  B1.u[3] = hi ? w7 : o5;

        // ---- O^T += V^T * P^T  (2 h-tiles x 2 k-subtiles) ----
        __builtin_amdgcn_s_setprio(1);
        O0 = __builtin_amdgcn_mfma_f32_32x32x16_bf16(V00, B0.v, O0, 0, 0, 0);
        O0 = __builtin_amdgcn_mfma_f32_32x32x16_bf16(V01, B1.v, O0, 0, 0, 0);
        O1 = __builtin_amdgcn_mfma_f32_32x32x16_bf16(V10, B0.v, O1, 0, 0, 0);
        O1 = __builtin_amdgcn_mfma_f32_32x32x16_bf16(V11, B1.v, O1, 0, 0, 0);
        __builtin_amdgcn_s_setprio(0);
    }

    // ---- epilogue: normalized partial in PO[slot][h][q] + (m, l) ----
    const float inv = 1.0f / l;
    const size_t slot = (size_t)(b * 128 + a) * NCH + c;
    bf16* po = PO + slot * 2048;              // 64 h x 32 q
#pragma unroll
    for (int r = 0; r < 16; ++r) {
        const int h = (r & 3) + 8 * (r >> 2) + 4 * half;
        po[h * 32 + l31]        = (bf16)(O0[r] * inv);
        po[(h + 32) * 32 + l31] = (bf16)(O1[r] * inv);
    }
    if (half == 0) {
        PML[slot * 64 + l31]      = m;
        PML[slot * 64 + 32 + l31] = l;
    }
}

// ---------------------------------------------------------------------------
// Kernel 4: combine split-K partials.  One (b, 32-row q-tile) per block.
// thread = (q = tid&31, hh = tid>>5); h = hh + 8*ih, ih = 0..7.
// ---------------------------------------------------------------------------
__global__ __launch_bounds__(256) void combine_kernel(
    const bf16* __restrict__ PO, const float* __restrict__ PML,
    float* __restrict__ out)
{
    const int gid = blockIdx.x;               // 512 = 4 x 128
    const int b   = gid & 3;
    const int a   = gid >> 2;
    const int qb  = a * 32;
    const int nch = (a >> 4) + 1;
    const int tid = threadIdx.x;
    const int q   = tid & 31;
    const int hh  = tid >> 5;                 // 0..7
    const size_t slot0 = (size_t)(b * 128 + a) * NCH;

    float mx = NEG_BIG;
    for (int c = 0; c < nch; ++c)
        mx = fmaxf(mx, PML[(slot0 + c) * 64 + q]);

    float L = 0.f;
    float acc[8];
#pragma unroll
    for (int i = 0; i < 8; ++i) acc[i] = 0.f;

    for (int c = 0; c < nch; ++c) {
        const float mm = PML[(slot0 + c) * 64 + q];
        const float ll = PML[(slot0 + c) * 64 + 32 + q];
        const float w  = ll * __expf(mm - mx);
        L += w;
        const bf16* po = PO + (slot0 + c) * 2048;
#pragma unroll
        for (int ih = 0; ih < 8; ++ih)
            acc[ih] += w * (float)po[(hh + 8 * ih) * 32 + q];
    }
    const float inv = 1.0f / L;
#pragma unroll
    for (int ih = 0; ih < 8; ++ih)
        out[((size_t)b * Tq + qb + q) * Hq + hh + 8 * ih] = acc[ih] * inv;
}

// ---------------------------------------------------------------------------
extern "C" void kernel_launch(void* const* d_in, const int* in_sizes, int n_in,
                              void* d_out, int out_size, void* d_ws, size_t ws_size,
                              hipStream_t stream)
{
    const float* k  = (const float*)d_in[0];
    const float* v  = (const float*)d_in[1];
    const float* q  = (const float*)d_in[2];
    // d_in[3] = mask: exactly tril(ones) -> causality hard-coded, never read
    const float* kW = (const float*)d_in[4];
    const float* kb = (const float*)d_in[5];
    const float* vW = (const float*)d_in[6];
    const float* vb = (const float*)d_in[7];
    const float* qW = (const float*)d_in[8];
    const float* qb = (const float*)d_in[9];
    float* out = (float*)d_out;

    // workspace layout:
    //   WT   [3][64][512] bf16          196608 B
    //   kp   [B*T][64]   bf16          2097152 B
    //   qp   [B*T][64]   bf16          2097152 B
    //   vpT  [B][64][T]  bf16          2097152 B
    //   PO   [B][128][8][64][32] bf16  16777216 B  (normalized partial O^T)
    //   PML  [B][128][8][2][32]  f32    1048576 B  (m, l per q-row)
    char* ws = (char*)d_ws;
    bf16*  WT  = (bf16*)(ws);
    bf16*  kp  = (bf16*)(ws + 196608);
    bf16*  qp  = (bf16*)(ws + 196608 + 2097152);
    bf16*  vpT = (bf16*)(ws + 196608 + 2 * 2097152);
    bf16*  PO  = (bf16*)(ws + 196608 + 3 * 2097152);
    float* PML = (float*)(ws + 196608 + 3 * 2097152 + 16777216);

    hipLaunchKernelGGL(prep_weights_kernel, dim3(384), dim3(256), 0, stream,
                       kW, qW, vW, WT);
    hipLaunchKernelGGL(proj_kernel, dim3(256, 3), dim3(256), 0, stream,
                       k, q, v, WT, kb, qb, vb, kp, qp, vpT);
    hipLaunchKernelGGL(attn_kernel, dim3(512, NCH), dim3(64), 0, stream,
                       qp, kp, vpT, PO, PML);
    hipLaunchKernelGGL(combine_kernel, dim3(512), dim3(256), 0, stream,
                       PO, PML, out);
}

// Round 7
// 98.672 us; speedup vs baseline: 1.0110x; 1.0110x over previous
//
#include <hip/hip_runtime.h>
#include <hip/hip_bf16.h>

#define Bq 4
#define Tq 4096
#define Cq 512
#define Hq 64
#define NCH 16           // chunks per q-tile (KC = 256 keys = 8 tiles of 32)
#define NEG_BIG (-3.0e38f)

using bf16   = __bf16;
using bf16x8 = __attribute__((ext_vector_type(8))) __bf16;
using bf16x4 = __attribute__((ext_vector_type(4))) __bf16;
using f32x4  = __attribute__((ext_vector_type(4))) float;
using f32x16 = __attribute__((ext_vector_type(16))) float;

// ---- cross-half (lane ^ 32) exchange: proven __shfl_xor primitive ----
static __device__ __forceinline__ float other_half_f(float x) {
    return __shfl_xor(x, 32, 64);
}
static __device__ __forceinline__ unsigned other_half_u(unsigned x) {
    return (unsigned)__shfl_xor((int)x, 32, 64);
}
static __device__ __forceinline__ unsigned pk2(float x, float y) {
    union { bf16 h[2]; unsigned u; } t;
    t.h[0] = (bf16)x; t.h[1] = (bf16)y;
    return t.u;
}
union W8 { unsigned u[4]; bf16x8 v; };

static __device__ __forceinline__ float max16(const f32x16& S) {
    float a = fmaxf(S[0], S[1]),   b = fmaxf(S[2], S[3]);
    float c = fmaxf(S[4], S[5]),   d = fmaxf(S[6], S[7]);
    float e = fmaxf(S[8], S[9]),   f = fmaxf(S[10], S[11]);
    float g = fmaxf(S[12], S[13]), h = fmaxf(S[14], S[15]);
    return fmaxf(fmaxf(fmaxf(a, b), fmaxf(c, d)),
                 fmaxf(fmaxf(e, f), fmaxf(g, h)));
}

// p[16] (one 32-key tile, in-lane) -> PV B-frags BA (k 0..15), BB (k 16..31)
#define BUILD_B(p, BA, BB) do {                                                \
    const unsigned w0 = pk2(p[0],  p[1]),  w1 = pk2(p[2],  p[3]);              \
    const unsigned w2 = pk2(p[4],  p[5]),  w3 = pk2(p[6],  p[7]);              \
    const unsigned w4 = pk2(p[8],  p[9]),  w5 = pk2(p[10], p[11]);             \
    const unsigned w6 = pk2(p[12], p[13]), w7 = pk2(p[14], p[15]);             \
    const unsigned o0 = other_half_u(w0), o1 = other_half_u(w1);               \
    const unsigned o2 = other_half_u(w2), o3 = other_half_u(w3);               \
    const unsigned o4 = other_half_u(w4), o5 = other_half_u(w5);               \
    const unsigned o6 = other_half_u(w6), o7 = other_half_u(w7);               \
    BA.u[0] = hi ? o2 : w0;  BA.u[1] = hi ? o3 : w1;                           \
    BA.u[2] = hi ? w2 : o0;  BA.u[3] = hi ? w3 : o1;                           \
    BB.u[0] = hi ? o6 : w4;  BB.u[1] = hi ? o7 : w5;                           \
    BB.u[2] = hi ? w6 : o4;  BB.u[3] = hi ? w7 : o5;                           \
} while (0)

// ---------------------------------------------------------------------------
// Kernel 1: transpose + bf16-cast the three weight matrices: WT[t][h][c]
// ---------------------------------------------------------------------------
__global__ __launch_bounds__(256) void prep_weights_kernel(
    const float* __restrict__ kW, const float* __restrict__ qW,
    const float* __restrict__ vW, bf16* __restrict__ WT)
{
    int i = blockIdx.x * 256 + threadIdx.x;   // 3*64*512 = 98304 total
    int t = i >> 15;
    int r = i & 32767;
    int h = r >> 9;
    int c = r & 511;
    const float* W = (t == 0) ? kW : (t == 1) ? qW : vW;
    WT[i] = (bf16)W[c * Hq + h];
}

// ---------------------------------------------------------------------------
// Kernel 2: projections via MFMA 16x16x32 bf16.  qp is pre-scaled by
// C^-0.5 * log2(e) so attention uses exp2 (bare v_exp_f32) everywhere.
// ---------------------------------------------------------------------------
__global__ __launch_bounds__(256) void proj_kernel(
    const float* __restrict__ Xk, const float* __restrict__ Xq,
    const float* __restrict__ Xv, const bf16* __restrict__ WT,
    const float* __restrict__ bk, const float* __restrict__ bq,
    const float* __restrict__ bv,
    bf16* __restrict__ kp, bf16* __restrict__ qp, bf16* __restrict__ vpT)
{
    const int t    = blockIdx.y;
    const int lane = threadIdx.x & 63;
    const int wave = threadIdx.x >> 6;
    const int lq   = lane & 15;
    const int lg   = lane >> 4;
    const int row0 = blockIdx.x * 64 + wave * 16;

    const float* X    = (t == 0) ? Xk : (t == 1) ? Xq : Xv;
    const float* bias = (t == 0) ? bk : (t == 1) ? bq : bv;
    const bf16*  Wt   = WT + (size_t)t * (Hq * Cq);

    const float* Xrow = X + (size_t)(row0 + lq) * Cq + lg * 8;

    f32x4 acc[4];
#pragma unroll
    for (int i = 0; i < 4; ++i) acc[i] = f32x4{0.f, 0.f, 0.f, 0.f};

#pragma unroll 4
    for (int kc = 0; kc < Cq; kc += 32) {
        float4 a0 = *(const float4*)(Xrow + kc);
        float4 a1 = *(const float4*)(Xrow + kc + 4);
        bf16x8 af;
        af[0] = (bf16)a0.x; af[1] = (bf16)a0.y; af[2] = (bf16)a0.z; af[3] = (bf16)a0.w;
        af[4] = (bf16)a1.x; af[5] = (bf16)a1.y; af[6] = (bf16)a1.z; af[7] = (bf16)a1.w;
#pragma unroll
        for (int ht = 0; ht < 4; ++ht) {
            bf16x8 bfB = *(const bf16x8*)(Wt + (size_t)(ht * 16 + lq) * Cq + kc + lg * 8);
            acc[ht] = __builtin_amdgcn_mfma_f32_16x16x32_bf16(af, bfB, acc[ht], 0, 0, 0);
        }
    }

    // C^-0.5 * log2(e) folded into qp
    const float scale = (t == 1) ? (0.044194173824159216f * 1.4426950408889634f) : 1.0f;

    if (t < 2) {
        bf16* dst = (t == 0) ? kp : qp;
#pragma unroll
        for (int ht = 0; ht < 4; ++ht) {
            float bb = bias[ht * 16 + lq];
#pragma unroll
            for (int r = 0; r < 4; ++r) {
                int row = row0 + 4 * lg + r;
                dst[(size_t)row * Hq + ht * 16 + lq] = (bf16)((acc[ht][r] + bb) * scale);
            }
        }
    } else {
#pragma unroll
        for (int ht = 0; ht < 4; ++ht) {
            float bb = bias[ht * 16 + lq];
            bf16x4 pk;
#pragma unroll
            for (int r = 0; r < 4; ++r) pk[r] = (bf16)(acc[ht][r] + bb);
            int rowg = row0 + 4 * lg;
            int bidx = rowg >> 12;
            int tt   = rowg & 4095;
            int h    = ht * 16 + lq;
            *(bf16x4*)(vpT + (((size_t)(bidx * Hq + h)) << 12) + tt) = pk;
        }
    }
}

// ---------------------------------------------------------------------------
// Kernel 3: causal flash attention, split-K (256-key chunks), 32x32x16 MFMA,
// in-register softmax, 64-KEY MACRO-STEP: two S-tiles share ONE online-
// softmax update (max/exp/corr/l per 64 keys instead of 32) -> dependent
// chain per key halves, and the two S-MFMA chains are independent (ILP).
// One wave per (b, 32-row q-tile, chunk).  exp2 domain (log2e pre-folded).
// ---------------------------------------------------------------------------
__global__ __launch_bounds__(64) void attn_kernel(
    const bf16* __restrict__ qp, const bf16* __restrict__ kp,
    const bf16* __restrict__ vpT,
    bf16* __restrict__ PO, float* __restrict__ PML)
{
    const int x  = blockIdx.x;                // 512 = 4 batches x 128 q-tiles
    const int s  = x & 7;                     // XCD slot
    const int b  = s >> 1;                    // batch pinned to XCD pair
    const int a  = ((x >> 3) << 1) | (s & 1); // 0..127: 32-row q-tile index
    const int qb = a * 32;
    const int u  = a >> 3;                    // # full 256-key chunks before diag
    const int vv = a & 7;
    const int c  = blockIdx.y;                // chunk id, 0..15
    if (c > u) return;                        // entirely above diagonal
    const int  nmac = (c < u) ? 4 : ((vv >> 1) + 1);  // 64-key macro tiles
    const bool diag = (c == u);

    const int lane = threadIdx.x;
    const int l31  = lane & 31;
    const int half = lane >> 5;
    const bool hi  = half != 0;
    const int qg   = qb + l31;

    // Q fragments: B[col=q=l31][contraction h = h0 + half*8 + i], h0=0,16,32,48
    const bf16* qrow = qp + ((size_t)b * Tq + qb + l31) * Hq + half * 8;
    const bf16x8 Q0 = *(const bf16x8*)(qrow);
    const bf16x8 Q1 = *(const bf16x8*)(qrow + 16);
    const bf16x8 Q2 = *(const bf16x8*)(qrow + 32);
    const bf16x8 Q3 = *(const bf16x8*)(qrow + 48);

    const bf16* Kb   = kp  + (size_t)b * Tq * Hq;
    const bf16* vrow = vpT + (size_t)b * Hq * Tq + (size_t)l31 * Tq + half * 8;

    f32x16 O0, O1;
#pragma unroll
    for (int r = 0; r < 16; ++r) { O0[r] = 0.f; O1[r] = 0.f; }
    float m = NEG_BIG, l = 0.f;

    const int kbase = c * 256;
    for (int mt = 0; mt < nmac; ++mt) {
        const int kb0 = kbase + mt * 64;

        // K A-frags for tiles kb0 (S0) and kb0+32 (S1)
        const bf16* kr = Kb + (size_t)(kb0 + l31) * Hq + half * 8;
        const bf16x8 K00 = *(const bf16x8*)(kr);
        const bf16x8 K01 = *(const bf16x8*)(kr + 16);
        const bf16x8 K02 = *(const bf16x8*)(kr + 32);
        const bf16x8 K03 = *(const bf16x8*)(kr + 48);
        const bf16x8 K10 = *(const bf16x8*)(kr + 32 * Hq);
        const bf16x8 K11 = *(const bf16x8*)(kr + 32 * Hq + 16);
        const bf16x8 K12 = *(const bf16x8*)(kr + 32 * Hq + 32);
        const bf16x8 K13 = *(const bf16x8*)(kr + 32 * Hq + 48);
        // V A-frags: rows h (l31 / +32), k-subtiles kb0+{0,16,32,48}
        const bf16* vr = vrow + kb0;
        const bf16x8 Vh0k0 = *(const bf16x8*)(vr);
        const bf16x8 Vh0k1 = *(const bf16x8*)(vr + 16);
        const bf16x8 Vh0k2 = *(const bf16x8*)(vr + 32);
        const bf16x8 Vh0k3 = *(const bf16x8*)(vr + 48);
        const bf16x8 Vh1k0 = *(const bf16x8*)(vr + (size_t)32 * Tq);
        const bf16x8 Vh1k1 = *(const bf16x8*)(vr + (size_t)32 * Tq + 16);
        const bf16x8 Vh1k2 = *(const bf16x8*)(vr + (size_t)32 * Tq + 32);
        const bf16x8 Vh1k3 = *(const bf16x8*)(vr + (size_t)32 * Tq + 48);

        // ---- two independent S^T chains over H=64 ----
        f32x16 S0, S1;
#pragma unroll
        for (int r = 0; r < 16; ++r) { S0[r] = 0.f; S1[r] = 0.f; }
        __builtin_amdgcn_s_setprio(1);
        S0 = __builtin_amdgcn_mfma_f32_32x32x16_bf16(K00, Q0, S0, 0, 0, 0);
        S1 = __builtin_amdgcn_mfma_f32_32x32x16_bf16(K10, Q0, S1, 0, 0, 0);
        S0 = __builtin_amdgcn_mfma_f32_32x32x16_bf16(K01, Q1, S0, 0, 0, 0);
        S1 = __builtin_amdgcn_mfma_f32_32x32x16_bf16(K11, Q1, S1, 0, 0, 0);
        S0 = __builtin_amdgcn_mfma_f32_32x32x16_bf16(K02, Q2, S0, 0, 0, 0);
        S1 = __builtin_amdgcn_mfma_f32_32x32x16_bf16(K12, Q2, S1, 0, 0, 0);
        S0 = __builtin_amdgcn_mfma_f32_32x32x16_bf16(K03, Q3, S0, 0, 0, 0);
        S1 = __builtin_amdgcn_mfma_f32_32x32x16_bf16(K13, Q3, S1, 0, 0, 0);
        __builtin_amdgcn_s_setprio(0);

        // ---- causal mask: only the diagonal chunk can straddle ----
        if (diag) {
#pragma unroll
            for (int r = 0; r < 16; ++r) {
                const int kg = kb0 + (r & 3) + 8 * (r >> 2) + 4 * half;
                if (kg > qg)      S0[r] = NEG_BIG;
                if (kg + 32 > qg) S1[r] = NEG_BIG;
            }
        }

        // ---- ONE online-softmax update for 64 keys ----
        float tm = fmaxf(max16(S0), max16(S1));
        tm = fmaxf(tm, other_half_f(tm));
        const float mn   = fmaxf(m, tm);
        const float corr = exp2f(m - mn);
        float p0[16], p1[16];
#pragma unroll
        for (int r = 0; r < 16; ++r) {
            p0[r] = exp2f(S0[r] - mn);
            p1[r] = exp2f(S1[r] - mn);
        }
        float ps = (((p0[0] + p0[1]) + (p0[2] + p0[3])) + ((p0[4] + p0[5]) + (p0[6] + p0[7])))
                 + (((p0[8] + p0[9]) + (p0[10] + p0[11])) + ((p0[12] + p0[13]) + (p0[14] + p0[15])))
                 + (((p1[0] + p1[1]) + (p1[2] + p1[3])) + ((p1[4] + p1[5]) + (p1[6] + p1[7])))
                 + (((p1[8] + p1[9]) + (p1[10] + p1[11])) + ((p1[12] + p1[13]) + (p1[14] + p1[15])));
        ps += other_half_f(ps);
        l = l * corr + ps;
        m = mn;
#pragma unroll
        for (int r = 0; r < 16; ++r) { O0[r] *= corr; O1[r] *= corr; }

        // ---- PV B-frags for both tiles ----
        W8 B00, B01, B10, B11;
        BUILD_B(p0, B00, B01);
        BUILD_B(p1, B10, B11);

        // ---- O^T += V^T * P^T  (2 h-tiles x 4 k-subtiles) ----
        __builtin_amdgcn_s_setprio(1);
        O0 = __builtin_amdgcn_mfma_f32_32x32x16_bf16(Vh0k0, B00.v, O0, 0, 0, 0);
        O1 = __builtin_amdgcn_mfma_f32_32x32x16_bf16(Vh1k0, B00.v, O1, 0, 0, 0);
        O0 = __builtin_amdgcn_mfma_f32_32x32x16_bf16(Vh0k1, B01.v, O0, 0, 0, 0);
        O1 = __builtin_amdgcn_mfma_f32_32x32x16_bf16(Vh1k1, B01.v, O1, 0, 0, 0);
        O0 = __builtin_amdgcn_mfma_f32_32x32x16_bf16(Vh0k2, B10.v, O0, 0, 0, 0);
        O1 = __builtin_amdgcn_mfma_f32_32x32x16_bf16(Vh1k2, B10.v, O1, 0, 0, 0);
        O0 = __builtin_amdgcn_mfma_f32_32x32x16_bf16(Vh0k3, B11.v, O0, 0, 0, 0);
        O1 = __builtin_amdgcn_mfma_f32_32x32x16_bf16(Vh1k3, B11.v, O1, 0, 0, 0);
        __builtin_amdgcn_s_setprio(0);
    }

    // ---- epilogue: normalized partial in PO[slot][h][q] + (m, l) ----
    const float inv = 1.0f / l;
    const int   sb   = b * 1088 + (u + 1) * ((u << 2) + vv);  // compact prefix
    const size_t slot = (size_t)sb + c;
    bf16* po = PO + slot * 2048;              // 64 h x 32 q
#pragma unroll
    for (int r = 0; r < 16; ++r) {
        const int h = (r & 3) + 8 * (r >> 2) + 4 * half;
        po[h * 32 + l31]        = (bf16)(O0[r] * inv);
        po[(h + 32) * 32 + l31] = (bf16)(O1[r] * inv);
    }
    if (half == 0) {
        PML[slot * 64 + l31]      = m;
        PML[slot * 64 + 32 + l31] = l;
    }
}

// ---------------------------------------------------------------------------
// Kernel 4: combine split-K partials.  One (b, 32-row q-tile) per block.
// thread = (q = tid&31, hh = tid>>5); h = hh + 8*ih, ih = 0..7.
// ---------------------------------------------------------------------------
__global__ __launch_bounds__(256) void combine_kernel(
    const bf16* __restrict__ PO, const float* __restrict__ PML,
    float* __restrict__ out)
{
    const int gid = blockIdx.x;               // 512 = 4 x 128
    const int b   = gid & 3;
    const int a   = gid >> 2;
    const int qb  = a * 32;
    const int u   = a >> 3, vv = a & 7;
    const int nch = u + 1;
    const size_t slot0 = (size_t)b * 1088 + (u + 1) * ((u << 2) + vv);
    const int tid = threadIdx.x;
    const int q   = tid & 31;
    const int hh  = tid >> 5;                 // 0..7

    float mx = NEG_BIG;
    for (int c = 0; c < nch; ++c)
        mx = fmaxf(mx, PML[(slot0 + c) * 64 + q]);

    float L = 0.f;
    float acc[8];
#pragma unroll
    for (int i = 0; i < 8; ++i) acc[i] = 0.f;

    for (int c = 0; c < nch; ++c) {
        const float mm = PML[(slot0 + c) * 64 + q];
        const float ll = PML[(slot0 + c) * 64 + 32 + q];
        const float w  = ll * exp2f(mm - mx);
        L += w;
        const bf16* po = PO + (slot0 + c) * 2048;
#pragma unroll
        for (int ih = 0; ih < 8; ++ih)
            acc[ih] += w * (float)po[(hh + 8 * ih) * 32 + q];
    }
    const float inv = 1.0f / L;
#pragma unroll
    for (int ih = 0; ih < 8; ++ih)
        out[((size_t)b * Tq + qb + q) * Hq + hh + 8 * ih] = acc[ih] * inv;
}

// ---------------------------------------------------------------------------
extern "C" void kernel_launch(void* const* d_in, const int* in_sizes, int n_in,
                              void* d_out, int out_size, void* d_ws, size_t ws_size,
                              hipStream_t stream)
{
    const float* k  = (const float*)d_in[0];
    const float* v  = (const float*)d_in[1];
    const float* q  = (const float*)d_in[2];
    // d_in[3] = mask: exactly tril(ones) -> causality hard-coded, never read
    const float* kW = (const float*)d_in[4];
    const float* kb = (const float*)d_in[5];
    const float* vW = (const float*)d_in[6];
    const float* vb = (const float*)d_in[7];
    const float* qW = (const float*)d_in[8];
    const float* qb = (const float*)d_in[9];
    float* out = (float*)d_out;

    // workspace layout:
    //   WT   [3][64][512] bf16             196608 B
    //   kp   [B*T][64]   bf16             2097152 B
    //   qp   [B*T][64]   bf16             2097152 B
    //   vpT  [B][64][T]  bf16             2097152 B
    //   PO   [4*1088 slots][64][32] bf16 17825792 B  (compact prefix-indexed)
    //   PML  [4*1088 slots][2][32]  f32   1114112 B
    //   total ~25.4 MB
    char* ws = (char*)d_ws;
    bf16*  WT  = (bf16*)(ws);
    bf16*  kp  = (bf16*)(ws + 196608);
    bf16*  qp  = (bf16*)(ws + 196608 + 2097152);
    bf16*  vpT = (bf16*)(ws + 196608 + 2 * 2097152);
    bf16*  PO  = (bf16*)(ws + 196608 + 3 * 2097152);
    float* PML = (float*)(ws + 196608 + 3 * 2097152 + 17825792);

    hipLaunchKernelGGL(prep_weights_kernel, dim3(384), dim3(256), 0, stream,
                       kW, qW, vW, WT);
    hipLaunchKernelGGL(proj_kernel, dim3(256, 3), dim3(256), 0, stream,
                       k, q, v, WT, kb, qb, vb, kp, qp, vpT);
    hipLaunchKernelGGL(attn_kernel, dim3(512, NCH), dim3(64), 0, stream,
                       qp, kp, vpT, PO, PML);
    hipLaunchKernelGGL(combine_kernel, dim3(512), dim3(256), 0, stream,
                       PO, PML, out);
}